// Round 1
// baseline (7596.266 us; speedup 1.0000x reference)
//
#include <hip/hip_runtime.h>
#include <math.h>

#define NDOF 4
#define NB   512
#define NT   64
#define ND   256
#define NS   (NDOF*ND)   // 1024 = grid-state width

#define BM 64
#define BN 32
#define BK 32

__device__ __forceinline__ float sigmoidf_(float v) {
    return 1.0f / (1.0f + expf(-v));
}

// One half-step. PHASE==1: per-dof LSTM cell, A = [x_t | h_in(own dof)], K=512,
// writes h_out=h_tmp. PHASE==2: grid coupling, A = h_in full row, K=1024,
// writes h_out=h_cur. m updated in place (each element owned by one thread).
template<int PHASE>
__global__ __launch_bounds__(256)
void lstm_phase(const float* __restrict__ x,
                const float* __restrict__ wU, const float* __restrict__ wF,
                const float* __restrict__ wO, const float* __restrict__ wC,
                const float* __restrict__ bU, const float* __restrict__ bF,
                const float* __restrict__ bO, const float* __restrict__ bC,
                const float* __restrict__ h_in,
                float* __restrict__ h_out,
                float* __restrict__ m,
                int t)
{
    const int K = (PHASE == 1) ? 2*ND : NS;
    const int ntn = ND / BN;   // 8
    const int ntm = NB / BM;   // 8

    const int blk = blockIdx.x;
    const int dof = blk / (ntm*ntn);
    const int rem = blk % (ntm*ntn);
    const int row0 = (rem / ntn) * BM;   // batch offset
    const int col0 = (rem % ntn) * BN;   // output-column offset

    // A stored transposed [k][m], pad +4 keeps 16B alignment for b128 reads.
    __shared__ float As[BK][BM+4];
    __shared__ float Bs[4][BK][BN+2];

    const int tid = threadIdx.x;
    const int tx = tid & 15;   // n: 16 groups x 2 cols
    const int ty = tid >> 4;   // m: 16 groups x 4 rows

    float acc[4][4][2];
    #pragma unroll
    for (int g = 0; g < 4; ++g)
        #pragma unroll
        for (int i = 0; i < 4; ++i) { acc[g][i][0] = 0.f; acc[g][i][1] = 0.f; }

    const float* wptr[4] = {wU, wF, wO, wC};

    // loader mapping
    const int lr = tid >> 2;          // A: row 0..63
    const int lk = (tid & 3) * 8;     // A: 8 consecutive k
    const int wr = tid >> 3;          // B: k-row 0..31
    const int wc = (tid & 7) * 4;     // B: 4 consecutive cols

    for (int k0 = 0; k0 < K; k0 += BK) {
        // ---- stage A tile (transposed) ----
        {
            const int b = row0 + lr;
            const float* src;
            if (PHASE == 1) {
                if (k0 + lk < ND)
                    src = &x[(((size_t)dof*NB + b)*NT + t)*ND + (k0 + lk)];
                else
                    src = &h_in[(size_t)b*NS + dof*ND + (k0 + lk - ND)];
            } else {
                src = &h_in[(size_t)b*NS + (k0 + lk)];
            }
            float av[8];
            #pragma unroll
            for (int u = 0; u < 8; ++u) av[u] = src[u];
            #pragma unroll
            for (int u = 0; u < 8; ++u) As[lk + u][lr] = av[u];
        }
        // ---- stage B tiles (4 gates) ----
        #pragma unroll
        for (int g = 0; g < 4; ++g) {
            const float* src = &wptr[g][((size_t)dof*K + (k0 + wr))*ND + col0 + wc];
            const float4 v = *reinterpret_cast<const float4*>(src);
            Bs[g][wr][wc+0] = v.x; Bs[g][wr][wc+1] = v.y;
            Bs[g][wr][wc+2] = v.z; Bs[g][wr][wc+3] = v.w;
        }
        __syncthreads();

        #pragma unroll
        for (int kk = 0; kk < BK; ++kk) {
            const float a0 = As[kk][ty*4+0];
            const float a1 = As[kk][ty*4+1];
            const float a2 = As[kk][ty*4+2];
            const float a3 = As[kk][ty*4+3];
            #pragma unroll
            for (int g = 0; g < 4; ++g) {
                const float b0 = Bs[g][kk][tx*2+0];
                const float b1 = Bs[g][kk][tx*2+1];
                acc[g][0][0] += a0*b0; acc[g][0][1] += a0*b1;
                acc[g][1][0] += a1*b0; acc[g][1][1] += a1*b1;
                acc[g][2][0] += a2*b0; acc[g][2][1] += a2*b1;
                acc[g][3][0] += a3*b0; acc[g][3][1] += a3*b1;
            }
        }
        __syncthreads();
    }

    // ---- fused LSTM epilogue ----
    #pragma unroll
    for (int i = 0; i < 4; ++i) {
        const int b = row0 + ty*4 + i;
        #pragma unroll
        for (int j = 0; j < 2; ++j) {
            const int col = col0 + tx*2 + j;
            const float pu = acc[0][i][j] + bU[dof*ND + col];
            const float pf = acc[1][i][j] + bF[dof*ND + col];
            const float po = acc[2][i][j] + bO[dof*ND + col];
            const float pc = acc[3][i][j] + bC[dof*ND + col];
            const float gu = sigmoidf_(pu);
            const float gf = sigmoidf_(pf);
            const float go = sigmoidf_(po);
            const float gc = tanhf(pc);
            const size_t idx = (size_t)b*NS + dof*ND + col;
            const float mnew = gf * m[idx] + gu * gc;
            m[idx] = mnew;
            h_out[idx] = tanhf(go * mnew);
        }
    }
}

// out[0][dof][b][j] = h, out[1][dof][b][j] = m  (state is stored [b][dof*ND+j])
__global__ void finalize_out(const float* __restrict__ h,
                             const float* __restrict__ m,
                             float* __restrict__ out)
{
    const size_t i = (size_t)blockIdx.x * blockDim.x + threadIdx.x;
    const size_t total = (size_t)NDOF*NB*ND;
    if (i >= total) return;
    const int j   = i % ND;
    const int b   = (i / ND) % NB;
    const int dof = i / ((size_t)ND*NB);
    const size_t idx = (size_t)b*NS + dof*ND + j;
    out[i]         = h[idx];
    out[total + i] = m[idx];
}

extern "C" void kernel_launch(void* const* d_in, const int* in_sizes, int n_in,
                              void* d_out, int out_size, void* d_ws, size_t ws_size,
                              hipStream_t stream)
{
    const float* x   = (const float*)d_in[0];
    const float* wu  = (const float*)d_in[1];
    const float* wf  = (const float*)d_in[2];
    const float* wo  = (const float*)d_in[3];
    const float* wc  = (const float*)d_in[4];
    const float* bu  = (const float*)d_in[5];
    const float* bf  = (const float*)d_in[6];
    const float* bo  = (const float*)d_in[7];
    const float* bc  = (const float*)d_in[8];
    const float* gwu = (const float*)d_in[9];
    const float* gwf = (const float*)d_in[10];
    const float* gwo = (const float*)d_in[11];
    const float* gwc = (const float*)d_in[12];
    const float* gbu = (const float*)d_in[13];
    const float* gbf = (const float*)d_in[14];
    const float* gbo = (const float*)d_in[15];
    const float* gbc = (const float*)d_in[16];

    float* h_cur = (float*)d_ws;                          // 2 MB
    float* mbuf  = h_cur + (size_t)NB*NS;                 // 2 MB
    float* h_tmp = mbuf  + (size_t)NB*NS;                 // 2 MB

    // zero-init h and m each call (harness poisons ws once; be deterministic)
    hipMemsetAsync(d_ws, 0, 2 * sizeof(float) * (size_t)NB * NS, stream);

    const dim3 grid(NDOF * (NB/BM) * (ND/BN));  // 4*8*8 = 256 blocks
    const dim3 block(256);

    for (int t = 0; t < NT; ++t) {
        lstm_phase<1><<<grid, block, 0, stream>>>(
            x, wu, wf, wo, wc, bu, bf, bo, bc, h_cur, h_tmp, mbuf, t);
        lstm_phase<2><<<grid, block, 0, stream>>>(
            nullptr, gwu, gwf, gwo, gwc, gbu, gbf, gbo, gbc, h_tmp, h_cur, mbuf, 0);
    }

    const size_t total = (size_t)NDOF*NB*ND;
    finalize_out<<<dim3((total + 255)/256), block, 0, stream>>>(h_cur, mbuf, (float*)d_out);
}

// Round 2
// 3053.481 us; speedup vs baseline: 2.4877x; 2.4877x over previous
//
#include <hip/hip_runtime.h>
#include <math.h>

#define NDOF 4
#define NB   512
#define NT   64
#define ND   256
#define NS   1024           // NDOF*ND = grid-state width

typedef __attribute__((ext_vector_type(8))) __bf16 bf16x8;
typedef __attribute__((ext_vector_type(4))) float  f32x4;

__device__ __forceinline__ void gll16(const void* g, void* l) {
    __builtin_amdgcn_global_load_lds(
        (const __attribute__((address_space(1))) unsigned int*)g,
        (__attribute__((address_space(3))) unsigned int*)l, 16, 0, 0);
}

__device__ __forceinline__ float sig_(float x) { return 1.0f / (1.0f + __expf(-x)); }
// overflow-safe tanh: exp argument always <= 0
__device__ __forceinline__ float tanh_(float x) {
    float e = __expf(-2.0f * fabsf(x));
    float t = (1.0f - e) / (1.0f + e);
    return copysignf(t, x);
}

// Build wT[n'][k] bf16 from w_g[dof][k][col] fp32, n' = dof*1024 + col*4 + g.
// Lanes map to consecutive n' at fixed k-chunk -> full 64B-line use on reads.
__global__ __launch_bounds__(256)
void transpose_weights(const float* __restrict__ wu, const float* __restrict__ wf,
                       const float* __restrict__ wo, const float* __restrict__ wcp,
                       const float* __restrict__ gwu, const float* __restrict__ gwf,
                       const float* __restrict__ gwo, const float* __restrict__ gwc,
                       __bf16* __restrict__ wT1, __bf16* __restrict__ wT2)
{
    int id = blockIdx.x * 256 + threadIdx.x;
    const int C1 = 4096 * 64;            // wT1 chunks (K=512 -> 64 16B-chunks per row)
    int K, np, kc;
    const float *s0, *s1, *s2, *s3;
    __bf16* dst;
    if (id < C1) { K = 512;  np = id & 4095; kc = id >> 12; dst = wT1; s0 = wu;  s1 = wf;  s2 = wo;  s3 = wcp; }
    else { id -= C1; K = 1024; np = id & 4095; kc = id >> 12; dst = wT2; s0 = gwu; s1 = gwf; s2 = gwo; s3 = gwc; }
    const int dof = np >> 10, q = np & 1023, col = q >> 2, g = q & 3;
    const float* w = (g == 0) ? s0 : (g == 1) ? s1 : (g == 2) ? s2 : s3;
    w += ((size_t)dof * K + kc * 8) * ND + col;
    bf16x8 o;
    #pragma unroll
    for (int j = 0; j < 8; ++j) o[j] = (__bf16)w[j * ND];
    *(bf16x8*)(dst + (size_t)np * K + kc * 8) = o;
}

// One half-step as a fused GEMM + LSTM epilogue.
// PHASE 1: A = [x_t | h(own dof)], K=512.  PHASE 2: A = full h row, K=1024.
// C columns n' = dof*1024 + col*4 + gate (gates adjacent -> self-contained epilogue).
template<int PHASE>
__global__ __launch_bounds__(256)
void lstm_mfma(const float* __restrict__ x,
               const __bf16* __restrict__ wT,
               const float* __restrict__ bU, const float* __restrict__ bF,
               const float* __restrict__ bO, const float* __restrict__ bC,
               const __bf16* __restrict__ h_in,
               __bf16* __restrict__ h_out,
               float* __restrict__ mst,
               float* __restrict__ hf32,
               int t)
{
    constexpr int K   = (PHASE == 1) ? 512 : 1024;
    constexpr int NIT = K / 64;

    // 64 KB: A double-buf [0,2048) 16B-units, B double-buf [2048,4096).
    // Layout per buffer: [kg 0..7][row 0..127] of 16B (8 bf16 along k).
    __shared__ bf16x8 smem[4096];

    const int tid  = threadIdx.x;
    const int lane = tid & 63;
    const int wv   = tid >> 6;
    const int wr   = (wv >> 1) * 64;    // wave row-half
    const int wcc  = (wv & 1) * 64;     // wave col-half
    const int nt   = blockIdx.x & 31;   // n'-tile; blk%8 -> XCD groups row-tiles per n'-tile
    const int rt   = blockIdx.x >> 5;
    const int r0   = rt * 128;
    const int n0   = nt * 128;
    const int dof  = n0 >> 10;

    f32x4 acc[4][4];
    #pragma unroll
    for (int mI = 0; mI < 4; ++mI)
        #pragma unroll
        for (int nI = 0; nI < 4; ++nI)
            acc[mI][nI] = (f32x4){0.f, 0.f, 0.f, 0.f};

    auto STAGE = [&](int it, int pb) {
        const int k0 = it * 64;
        // B tile: wT rows n0..n0+127, k0..k0+63 (k-contiguous 16B chunks)
        #pragma unroll
        for (int i = 0; i < 4; ++i) {
            const int c  = tid + 256 * i;
            const int nr = c & 127;
            const int kg = c >> 7;
            gll16(wT + (size_t)(n0 + nr) * K + k0 + kg * 8,
                  &smem[2048 + pb * 1024 + kg * 128 + nr]);
        }
        if (PHASE == 1 && k0 < 256) {
            // x part: fp32 -> bf16 reg-staged
            #pragma unroll
            for (int i = 0; i < 4; ++i) {
                const int c   = tid + 256 * i;
                const int row = c & 127;
                const int kg  = c >> 7;
                const float* sx = x + (((size_t)dof * NB + r0 + row) * NT + t) * ND + k0 + kg * 8;
                float4 v0 = *(const float4*)sx;
                float4 v1 = *(const float4*)(sx + 4);
                bf16x8 o;
                o[0] = (__bf16)v0.x; o[1] = (__bf16)v0.y; o[2] = (__bf16)v0.z; o[3] = (__bf16)v0.w;
                o[4] = (__bf16)v1.x; o[5] = (__bf16)v1.y; o[6] = (__bf16)v1.z; o[7] = (__bf16)v1.w;
                smem[pb * 1024 + kg * 128 + row] = o;
            }
        } else {
            // h part: bf16 direct global->LDS (dest = wave-uniform base + lane*16: linear)
            const int base = (PHASE == 1) ? (dof * ND - 256) : 0;
            #pragma unroll
            for (int i = 0; i < 4; ++i) {
                const int c   = tid + 256 * i;
                const int row = c & 127;
                const int kg  = c >> 7;
                gll16(h_in + (size_t)(r0 + row) * NS + base + k0 + kg * 8,
                      &smem[pb * 1024 + kg * 128 + row]);
            }
        }
    };

    STAGE(0, 0);
    __syncthreads();
    int pb = 0;
    for (int it = 0; it < NIT; ++it) {
        if (it + 1 < NIT) STAGE(it + 1, pb ^ 1);   // overlap staging with compute
        #pragma unroll
        for (int sub = 0; sub < 2; ++sub) {
            const int kq = sub * 4 + (lane >> 4);
            bf16x8 a[4], b[4];
            #pragma unroll
            for (int mI = 0; mI < 4; ++mI)
                a[mI] = smem[pb * 1024 + kq * 128 + wr + mI * 16 + (lane & 15)];
            #pragma unroll
            for (int nI = 0; nI < 4; ++nI)
                b[nI] = smem[2048 + pb * 1024 + kq * 128 + wcc + nI * 16 + (lane & 15)];
            #pragma unroll
            for (int mI = 0; mI < 4; ++mI)
                #pragma unroll
                for (int nI = 0; nI < 4; ++nI)
                    acc[mI][nI] = __builtin_amdgcn_mfma_f32_16x16x32_bf16(a[mI], b[nI], acc[mI][nI], 0, 0, 0);
        }
        __syncthreads();   // drains staging loads + compute reads
        pb ^= 1;
    }

    // ---- epilogue: acc -> LDS (reuse smem as 128x128 f32 = 64 KB) ----
    float* P = (float*)smem;
    #pragma unroll
    for (int mI = 0; mI < 4; ++mI)
        #pragma unroll
        for (int nI = 0; nI < 4; ++nI)
            #pragma unroll
            for (int r = 0; r < 4; ++r)
                P[(wr + mI * 16 + (lane >> 4) * 4 + r) * 128 + wcc + nI * 16 + (lane & 15)] = acc[mI][nI][r];
    __syncthreads();

    const int colq = tid & 31;                 // col within this block's 32 cols
    const int rg   = tid >> 5;                 // 8 row groups of 16
    const int colg = ((n0 & 1023) >> 2) + colq;
    const int scol = dof * ND + colg;
    const float bu = bU[dof * ND + colg];
    const float bfv = bF[dof * ND + colg];
    const float bov = bO[dof * ND + colg];
    const float bcv = bC[dof * ND + colg];
    #pragma unroll
    for (int i = 0; i < 16; ++i) {
        const int row = rg * 16 + i;
        const f32x4 p = *(const f32x4*)&P[row * 128 + colq * 4];  // (pu,pf,po,pc)
        const float gu = sig_(p[0] + bu);
        const float gf = sig_(p[1] + bfv);
        const float go = sig_(p[2] + bov);
        const float gc = tanh_(p[3] + bcv);
        const size_t mi = (size_t)(r0 + row) * NS + scol;
        const float mn = gf * mst[mi] + gu * gc;
        mst[mi] = mn;
        const float hv = tanh_(go * mn);
        h_out[mi] = (__bf16)hv;
        if (PHASE == 2) hf32[mi] = hv;   // fp32 h for final output (no bf16 rounding)
    }
}

__global__ __launch_bounds__(256)
void finalize_out(const float* __restrict__ hf, const float* __restrict__ mst,
                  float* __restrict__ out)
{
    const int i = blockIdx.x * 256 + threadIdx.x;   // < 524288 exact
    const int j   = i & 255;
    const int b   = (i >> 8) & 511;
    const int dof = i >> 17;
    const size_t idx = (size_t)b * NS + dof * ND + j;
    out[i]          = hf[idx];
    out[524288 + i] = mst[idx];
}

extern "C" void kernel_launch(void* const* d_in, const int* in_sizes, int n_in,
                              void* d_out, int out_size, void* d_ws, size_t ws_size,
                              hipStream_t stream)
{
    const float* x   = (const float*)d_in[0];
    const float* wu  = (const float*)d_in[1];
    const float* wf  = (const float*)d_in[2];
    const float* wo  = (const float*)d_in[3];
    const float* wc  = (const float*)d_in[4];
    const float* bu  = (const float*)d_in[5];
    const float* bff = (const float*)d_in[6];
    const float* bo  = (const float*)d_in[7];
    const float* bc  = (const float*)d_in[8];
    const float* gwu = (const float*)d_in[9];
    const float* gwf = (const float*)d_in[10];
    const float* gwo = (const float*)d_in[11];
    const float* gwc = (const float*)d_in[12];
    const float* gbu = (const float*)d_in[13];
    const float* gbf = (const float*)d_in[14];
    const float* gbo = (const float*)d_in[15];
    const float* gbc = (const float*)d_in[16];

    char* ws = (char*)d_ws;
    __bf16* wT1 = (__bf16*)ws;                      //  4 MB  [4096][512]
    __bf16* wT2 = (__bf16*)(ws + (4  << 20));       //  8 MB  [4096][1024]
    __bf16* h_a = (__bf16*)(ws + (12 << 20));       //  1 MB  h state (bf16)
    float*  mst = (float*) (ws + (13 << 20));       //  2 MB  m state (fp32)
    __bf16* h_b = (__bf16*)(ws + (15 << 20));       //  1 MB  h after phase 1
    float*  hf  = (float*) (ws + (16 << 20));       //  2 MB  h (fp32) for output

    transpose_weights<<<3072, 256, 0, stream>>>(wu, wf, wo, wc, gwu, gwf, gwo, gwc, wT1, wT2);
    hipMemsetAsync(ws + (12 << 20), 0, 3 << 20, stream);   // zero h_a + m

    for (int t = 0; t < NT; ++t) {
        lstm_mfma<1><<<128, 256, 0, stream>>>(x, wT1, bu,  bff, bo,  bc,  h_a, h_b, mst, hf, t);
        lstm_mfma<2><<<128, 256, 0, stream>>>(x, wT2, gbu, gbf, gbo, gbc, h_b, h_a, mst, hf, 0);
    }

    finalize_out<<<2048, 256, 0, stream>>>(hf, mst, (float*)d_out);
}